// Round 8
// baseline (203.151 us; speedup 1.0000x reference)
//
#include <hip/hip_runtime.h>
#include <hip/hip_bf16.h>
#include <stdint.h>

#define CC 256
#define CQD 32
#define NND 4096

typedef __bf16 bf16x8 __attribute__((ext_vector_type(8)));
typedef float f32x4 __attribute__((ext_vector_type(4)));
typedef float f32x16 __attribute__((ext_vector_type(16)));

__device__ __forceinline__ bf16x8 ld_bf16x8(const __bf16* p) {
    return *reinterpret_cast<const bf16x8*>(p);
}

// ---------------- weight conversion ----------------
__global__ __launch_bounds__(256) void prep_weights(
    const float* __restrict__ wq, const float* __restrict__ wk,
    const float* __restrict__ wv, __bf16* __restrict__ wqkb,
    __bf16* __restrict__ wvb) {
    int i = blockIdx.x * 256 + threadIdx.x;
    if (i < 32 * 256) {
        wqkb[i] = (__bf16)wq[i];
    } else if (i < 64 * 256) {
        wqkb[i] = (__bf16)wk[i - 32 * 256];
    } else {
        int j = i - 64 * 256;
        if (j < 256 * 256) wvb[j] = (__bf16)wv[j];
    }
}

// ---------------- fused transpose + q/k/v projection ----------------
// (byte-identical to R10 — proj plateaued ~92 us across 5 variants; once
// attention drops below it, proj finally surfaces in the rocprof top-5)
__global__ __launch_bounds__(256, 4) void proj_qkv(
    const float* __restrict__ x, const __bf16* __restrict__ wqkb,
    const __bf16* __restrict__ wvb, const float* __restrict__ bq,
    const float* __restrict__ bk, const float* __restrict__ bv,
    __bf16* __restrict__ qb, __bf16* __restrict__ kb,
    __bf16* __restrict__ vb) {
    __shared__ __align__(16) __bf16 xt[32 * 256];  // 16 KB, xor-swizzled rows
    __shared__ __align__(16) __bf16 wt[320 * 32];  // 20 KB: rows 0..63 qk, 64..319 v

    const int blk = blockIdx.x;
    const int b = blk & 7;
    const int n0 = (blk >> 3) * 32;
    const int tid = threadIdx.x;
    const int lane = tid & 63;
    const int w = tid >> 6;

    const __bf16* wsrc = wqkb + (size_t)(lane >> 2) * CC + (lane & 3) * 8;

#pragma unroll
    for (int i = 0; i < 5; i++) {
        int ins = w * 5 + i;
        __builtin_amdgcn_global_load_lds(
            (const __attribute__((address_space(1))) void*)(wsrc + (size_t)ins * 16 * CC),
            (__attribute__((address_space(3))) void*)(&wt[ins * 512]), 16, 0, 0);
    }

    // phase 1: x[c][n] -> xt[n][c], float4 along n, all 8 loads in flight
    {
        const int cl = tid >> 3;  // c-local 0..31
        const int ng = tid & 7;   // n-group 0..7 (4 n each)
        const float* xrow = x + (size_t)b * CC * NND + n0 + ng * 4;
        f32x4 xv[8];
#pragma unroll
        for (int p = 0; p < 8; p++)
            xv[p] = *reinterpret_cast<const f32x4*>(xrow + (size_t)(p * 32 + cl) * NND);
#pragma unroll
        for (int p = 0; p < 8; p++) {
            int c = p * 32 + cl;
            int c8 = c >> 3;
#pragma unroll
            for (int j = 0; j < 4; j++) {
                int row = ng * 4 + j;
                xt[row * 256 + ((c8 ^ (row & 7)) * 8) + (c & 7)] = (__bf16)xv[p][j];
            }
        }
    }
    __syncthreads();  // full drain: xt visible AND prologue gll landed

    const int l15 = lane & 15;
    const int quad = lane >> 4;
    const f32x4 fzero = {0.f, 0.f, 0.f, 0.f};
    f32x4 aqk[2];
    f32x4 av[4][2];
#pragma unroll
    for (int i = 0; i < 2; i++) aqk[i] = fzero;
#pragma unroll
    for (int i = 0; i < 4; i++)
#pragma unroll
        for (int j = 0; j < 2; j++) av[i][j] = fzero;

#pragma unroll
    for (int t = 0; t < 8; t++) {
        const int k0 = t * 32;
        bf16x8 bfx[2];
#pragma unroll
        for (int nt = 0; nt < 2; nt++) {
            int row = nt * 16 + l15;
            int g = (k0 >> 3) + quad;
            bfx[nt] = ld_bf16x8(&xt[row * 256 + ((g ^ (row & 7)) * 8)]);
        }
        bf16x8 aqf = ld_bf16x8(&wt[(w * 16 + l15) * 32 + quad * 8]);
        bf16x8 avf[4];
#pragma unroll
        for (int mt = 0; mt < 4; mt++)
            avf[mt] = ld_bf16x8(&wt[(64 + (w * 4 + mt) * 16 + l15) * 32 + quad * 8]);
        asm volatile("s_waitcnt lgkmcnt(0)" ::: "memory");
        __builtin_amdgcn_s_barrier();  // A: all frag reads complete -> wt free
        int kn = (k0 + 32) & 255;
#pragma unroll
        for (int i = 0; i < 5; i++) {
            int ins = w * 5 + i;
            __builtin_amdgcn_global_load_lds(
                (const __attribute__((address_space(1))) void*)(wsrc + (size_t)ins * 16 * CC + kn),
                (__attribute__((address_space(3))) void*)(&wt[ins * 512]), 16, 0, 0);
        }
#pragma unroll
        for (int nt = 0; nt < 2; nt++)
            aqk[nt] = __builtin_amdgcn_mfma_f32_16x16x32_bf16(aqf, bfx[nt], aqk[nt], 0, 0, 0);
#pragma unroll
        for (int mt = 0; mt < 4; mt++)
#pragma unroll
            for (int nt = 0; nt < 2; nt++)
                av[mt][nt] = __builtin_amdgcn_mfma_f32_16x16x32_bf16(avf[mt], bfx[nt], av[mt][nt], 0, 0, 0);
        asm volatile("s_waitcnt vmcnt(0)" ::: "memory");
        __builtin_amdgcn_s_barrier();  // B: next slice resident
    }

    {
        const int ob = (w & 1) * 16 + quad * 4;
        const float* bias = (w < 2) ? bq : bk;
        __bf16* base = (w < 2) ? qb : kb;
#pragma unroll
        for (int nt = 0; nt < 2; nt++) {
            int n = n0 + nt * 16 + l15;
            union { ushort4 u; __bf16 h[4]; } pk;
#pragma unroll
            for (int r = 0; r < 4; r++) pk.h[r] = (__bf16)(aqk[nt][r] + bias[ob + r]);
            *reinterpret_cast<ushort4*>(base + ((size_t)b * NND + n) * CQD + ob) = pk.u;
        }
    }
    __syncthreads();
#pragma unroll
    for (int mt = 0; mt < 4; mt++) {
#pragma unroll
        for (int nt = 0; nt < 2; nt++) {
#pragma unroll
            for (int r = 0; r < 4; r++) {
                int c = (w * 4 + mt) * 16 + quad * 4 + r;
                int nl = nt * 16 + l15;
                xt[c * 32 + (((nl >> 3) ^ (c & 3)) * 8) + (nl & 7)] =
                    (__bf16)(av[mt][nt][r] + bv[c]);
            }
        }
    }
    __syncthreads();
#pragma unroll
    for (int s = 0; s < 4; s++) {
        int c = s * 64 + (tid >> 2);
        int nc = tid & 3;
        bf16x8 vv = ld_bf16x8(&xt[c * 32 + ((nc ^ (c & 3)) * 8)]);
        *reinterpret_cast<bf16x8*>(vb + ((size_t)b * CC + c) * NND + n0 + nc * 8) = vv;
    }
}

// ---------------- fused flash attention + epilogue ----------------
// R11 vs R10: ONE change — PV switched from 16 x mfma_16x16x32 to
// 8 x mfma_32x32x16 per wave-step. Measured rates (m119): 32x32x16 =
// 4060 FLOP/cyc vs 3380 for 16x16x32 (~17% cheaper) and half the issue
// slots + half the PV addressing VALU. The wave's 32-c slice is exactly
// one 32x32 m-tile: A = V[w*32+(lane&31)][kk*16+(lane>>5)*8..], B =
// P[it*32+(lane&31)][same k], 4 K-steps x 2 i-tiles. A/B k-half
// conventions cancel (same mapping on both operands). C/D layout (m74/
// m101-verified): col=lane&31, c-row=(reg&3)+8*(reg>>2)+4*(lane>>5).
// QK^T/softmax/staging/barriers byte-identical to R10.
__global__ __launch_bounds__(512, 4) void attention(
    const __bf16* __restrict__ qb, const __bf16* __restrict__ kb,
    const __bf16* __restrict__ vb, const float* __restrict__ gamma,
    const float* __restrict__ x, float* __restrict__ out) {
    __shared__ __align__(16) __bf16 Vt[CC * 64];     // 32768 B, swizzled rows
    __shared__ __align__(16) __bf16 Pt[2][64 * 72];  // 2 x 9216 B, [i][j] stride 72
    __shared__ float lL[2][64];

    const int blk = blockIdx.x;
    const int b = blk & 7;
    const int i0 = (blk >> 3) * 64;
    const int tid = threadIdx.x;
    const int w = tid >> 6;     // 0..7
    const int jh = w >> 2;      // j-half 0/1
    const int iw = w & 3;       // i-slab 0..3
    const int lane = tid & 63;
    const int l15 = lane & 15;
    const int quad = lane >> 4;
    const int l31 = lane & 31;
    const int hi = lane >> 5;
    const f32x4 fzero = {0.f, 0.f, 0.f, 0.f};

    // Q fragment (B-operand): n=i = i0 + iw*16 + l15, k(c) = quad*8..
    bf16x8 qf = ld_bf16x8(qb + ((size_t)b * NND + i0 + iw * 16 + l15) * CQD + quad * 8);

    // K fragments (A-operand), this wave's j-half: j = jh*32 + jt*16 + l15
    const __bf16* kbase = kb + ((size_t)b * NND + jh * 32 + l15) * CQD + quad * 8;
    bf16x8 kf[2];
#pragma unroll
    for (int jt = 0; jt < 2; jt++)
        kf[jt] = ld_bf16x8(kbase + (size_t)(jt * 16) * CQD);

    // global_load_lds source: wave stages c-rows w*32..w*32+31 (wave-private)
    const int vrow = lane >> 3;  // 0..7
    const int vswz = ((lane & 7) ^ vrow) * 8;
    const __bf16* vsrc = vb + ((size_t)(b * CC + w * 32 + vrow)) * NND + vswz;
    __bf16* vdstb = &Vt[(w * 32) * 64];  // wave-uniform base; +lane*16B by HW

    // PV accumulators: 2 i-tiles of 32x32; c = w*32 + crow(reg,hi), i = it*32+l31
    f32x16 acc[2];
#pragma unroll
    for (int it = 0; it < 2; it++)
#pragma unroll
        for (int r = 0; r < 16; r++) acc[it][r] = 0.f;
    float l_i = 0.f;

#define ATTN_STEP(J0, BUF)                                                    \
    {                                                                         \
        _Pragma("unroll")                                                     \
        for (int t = 0; t < 4; t++) {                                         \
            __builtin_amdgcn_global_load_lds(                                 \
                (const __attribute__((address_space(1))) void*)(vsrc + (size_t)t * 8 * NND + (J0)), \
                (__attribute__((address_space(3))) void*)(vdstb + t * 8 * 64), 16, 0, 0); \
        }                                                                     \
        __builtin_amdgcn_sched_barrier(0); /* pin glls first: vmcnt count */  \
        f32x4 sT[2];                                                          \
        _Pragma("unroll")                                                     \
        for (int jt = 0; jt < 2; jt++)                                        \
            sT[jt] = __builtin_amdgcn_mfma_f32_16x16x32_bf16(kf[jt], qf, fzero, 0, 0, 0); \
        const int jn = ((J0) + 64) & (NND - 1);                               \
        _Pragma("unroll")                                                     \
        for (int jt = 0; jt < 2; jt++)                                        \
            kf[jt] = ld_bf16x8(kbase + (size_t)(jn + jt * 16) * CQD);         \
        float ps = 0.f;                                                       \
        _Pragma("unroll")                                                     \
        for (int jt = 0; jt < 2; jt++) {                                      \
            union { ushort4 u4; __bf16 h[4]; } pk;                            \
            _Pragma("unroll")                                                 \
            for (int r = 0; r < 4; r++) {                                     \
                float p = __builtin_amdgcn_exp2f(                             \
                    sT[jt][r] * 1.44269504f - 28.85390082f);                  \
                ps += p;                                                      \
                pk.h[r] = (__bf16)p;                                          \
            }                                                                 \
            *reinterpret_cast<ushort4*>(                                      \
                &Pt[BUF][(iw * 16 + l15) * 72 + jh * 32 + jt * 16 + quad * 4]) = pk.u4; \
        }                                                                     \
        l_i += ps;                                                            \
        asm volatile("s_waitcnt lgkmcnt(0)" ::: "memory");                    \
        __builtin_amdgcn_s_barrier();                                         \
        asm volatile("s_waitcnt vmcnt(2)" ::: "memory");                      \
        __builtin_amdgcn_sched_barrier(0);                                    \
        __builtin_amdgcn_s_setprio(1);                                        \
        _Pragma("unroll")                                                     \
        for (int kk = 0; kk < 4; kk++) {                                      \
            int slot = (((kk * 2 + hi) ^ (l31 & 7)) * 8);                     \
            bf16x8 vfrag = ld_bf16x8(&Vt[(w * 32 + l31) * 64 + slot]);        \
            _Pragma("unroll")                                                 \
            for (int it = 0; it < 2; it++) {                                  \
                bf16x8 pfrag = ld_bf16x8(                                     \
                    &Pt[BUF][(it * 32 + l31) * 72 + kk * 16 + hi * 8]);       \
                acc[it] = __builtin_amdgcn_mfma_f32_32x32x16_bf16(            \
                    vfrag, pfrag, acc[it], 0, 0, 0);                          \
            }                                                                 \
        }                                                                     \
        __builtin_amdgcn_s_setprio(0);                                        \
    }

    for (int j0 = 0; j0 < NND; j0 += 128) {
        ATTN_STEP(j0, 0)
        ATTN_STEP(j0 + 64, 1)
    }
#undef ATTN_STEP

    // epilogue: combine per-half l sums, then out = gamma * O / l + x
    l_i += __shfl_xor(l_i, 16);
    l_i += __shfl_xor(l_i, 32);
    if (quad == 0) lL[jh][iw * 16 + l15] = l_i;
    __syncthreads();
    float g = gamma[0];
#pragma unroll
    for (int it = 0; it < 2; it++) {
        int i = i0 + it * 32 + l31;
        float linv = 1.0f / (lL[0][it * 32 + l31] + lL[1][it * 32 + l31]);
#pragma unroll
        for (int r = 0; r < 16; r++) {
            int c = w * 32 + (r & 3) + 8 * (r >> 2) + 4 * hi;
            size_t off = ((size_t)b * CC + c) * NND + i;
            out[off] = g * (acc[it][r] * linv) + x[off];
        }
    }
}

extern "C" void kernel_launch(void* const* d_in, const int* in_sizes, int n_in,
                              void* d_out, int out_size, void* d_ws, size_t ws_size,
                              hipStream_t stream) {
    const float* x = (const float*)d_in[0];
    const float* wq = (const float*)d_in[1];
    const float* bq = (const float*)d_in[2];
    const float* wk = (const float*)d_in[3];
    const float* bk = (const float*)d_in[4];
    const float* wv = (const float*)d_in[5];
    const float* bv = (const float*)d_in[6];
    const float* gamma = (const float*)d_in[7];
    float* out = (float*)d_out;

    char* ws = (char*)d_ws;
    __bf16* qb = (__bf16*)ws;                       // 8*4096*32*2  = 2097152
    __bf16* kb = (__bf16*)(ws + 2097152);           // 2097152
    __bf16* vb = (__bf16*)(ws + 2 * 2097152);       // 8*256*4096*2 = 16777216
    __bf16* wqkb = (__bf16*)(ws + 2 * 2097152 + 16777216);           // 32768 (64 rows)
    __bf16* wvb = (__bf16*)(ws + 2 * 2097152 + 16777216 + 32768);    // 131072 (256 rows)

    prep_weights<<<320, 256, 0, stream>>>(wq, wk, wv, wqkb, wvb);
    proj_qkv<<<1024, 256, 0, stream>>>(x, wqkb, wvb, bq, bk, bv, qb, kb, vb);
    attention<<<512, 512, 0, stream>>>(qb, kb, vb, gamma, x, out);
}

// Round 9
// 200.992 us; speedup vs baseline: 1.0107x; 1.0107x over previous
//
#include <hip/hip_runtime.h>
#include <hip/hip_bf16.h>
#include <stdint.h>

#define CC 256
#define CQD 32
#define NND 4096

typedef __bf16 bf16x8 __attribute__((ext_vector_type(8)));
typedef float f32x4 __attribute__((ext_vector_type(4)));
typedef float f32x16 __attribute__((ext_vector_type(16)));

__device__ __forceinline__ bf16x8 ld_bf16x8(const __bf16* p) {
    return *reinterpret_cast<const bf16x8*>(p);
}

// ---------------- weight conversion ----------------
__global__ __launch_bounds__(256) void prep_weights(
    const float* __restrict__ wq, const float* __restrict__ wk,
    const float* __restrict__ wv, __bf16* __restrict__ wqkb,
    __bf16* __restrict__ wvb) {
    int i = blockIdx.x * 256 + threadIdx.x;
    if (i < 32 * 256) {
        wqkb[i] = (__bf16)wq[i];
    } else if (i < 64 * 256) {
        wqkb[i] = (__bf16)wk[i - 32 * 256];
    } else {
        int j = i - 64 * 256;
        if (j < 256 * 256) wvb[j] = (__bf16)wv[j];
    }
}

// ---------------- fused transpose + q/k/v projection ----------------
// R12 vs R11: TWO-LINE block remap testing the DRAM-row-locality theory.
// Old: b = blk&7 -> concurrent blocks scatter over 8 batches; each block
// reads 256 x-rows at 128B/row, rows 16KB apart -> ~1 DRAM row activation
// per 128B. New: b = blk>>7 -> the 128 co-resident blocks of one batch
// tile the n-axis densely; 8 adjacent blocks cover 1KB contiguous of each
// x-row. (Attention keeps its own b = blk&7 mapping; unaffected.)
// Everything else byte-identical to R10/R11 proj.
__global__ __launch_bounds__(256, 4) void proj_qkv(
    const float* __restrict__ x, const __bf16* __restrict__ wqkb,
    const __bf16* __restrict__ wvb, const float* __restrict__ bq,
    const float* __restrict__ bk, const float* __restrict__ bv,
    __bf16* __restrict__ qb, __bf16* __restrict__ kb,
    __bf16* __restrict__ vb) {
    __shared__ __align__(16) __bf16 xt[32 * 256];  // 16 KB, xor-swizzled rows
    __shared__ __align__(16) __bf16 wt[320 * 32];  // 20 KB: rows 0..63 qk, 64..319 v

    const int blk = blockIdx.x;
    const int b = blk >> 7;            // R12: batch-major remap
    const int n0 = (blk & 127) * 32;   // R12: adjacent blocks = adjacent n
    const int tid = threadIdx.x;
    const int lane = tid & 63;
    const int w = tid >> 6;

    const __bf16* wsrc = wqkb + (size_t)(lane >> 2) * CC + (lane & 3) * 8;

#pragma unroll
    for (int i = 0; i < 5; i++) {
        int ins = w * 5 + i;
        __builtin_amdgcn_global_load_lds(
            (const __attribute__((address_space(1))) void*)(wsrc + (size_t)ins * 16 * CC),
            (__attribute__((address_space(3))) void*)(&wt[ins * 512]), 16, 0, 0);
    }

    // phase 1: x[c][n] -> xt[n][c], float4 along n, all 8 loads in flight
    {
        const int cl = tid >> 3;  // c-local 0..31
        const int ng = tid & 7;   // n-group 0..7 (4 n each)
        const float* xrow = x + (size_t)b * CC * NND + n0 + ng * 4;
        f32x4 xv[8];
#pragma unroll
        for (int p = 0; p < 8; p++)
            xv[p] = *reinterpret_cast<const f32x4*>(xrow + (size_t)(p * 32 + cl) * NND);
#pragma unroll
        for (int p = 0; p < 8; p++) {
            int c = p * 32 + cl;
            int c8 = c >> 3;
#pragma unroll
            for (int j = 0; j < 4; j++) {
                int row = ng * 4 + j;
                xt[row * 256 + ((c8 ^ (row & 7)) * 8) + (c & 7)] = (__bf16)xv[p][j];
            }
        }
    }
    __syncthreads();  // full drain: xt visible AND prologue gll landed

    const int l15 = lane & 15;
    const int quad = lane >> 4;
    const f32x4 fzero = {0.f, 0.f, 0.f, 0.f};
    f32x4 aqk[2];
    f32x4 av[4][2];
#pragma unroll
    for (int i = 0; i < 2; i++) aqk[i] = fzero;
#pragma unroll
    for (int i = 0; i < 4; i++)
#pragma unroll
        for (int j = 0; j < 2; j++) av[i][j] = fzero;

#pragma unroll
    for (int t = 0; t < 8; t++) {
        const int k0 = t * 32;
        bf16x8 bfx[2];
#pragma unroll
        for (int nt = 0; nt < 2; nt++) {
            int row = nt * 16 + l15;
            int g = (k0 >> 3) + quad;
            bfx[nt] = ld_bf16x8(&xt[row * 256 + ((g ^ (row & 7)) * 8)]);
        }
        bf16x8 aqf = ld_bf16x8(&wt[(w * 16 + l15) * 32 + quad * 8]);
        bf16x8 avf[4];
#pragma unroll
        for (int mt = 0; mt < 4; mt++)
            avf[mt] = ld_bf16x8(&wt[(64 + (w * 4 + mt) * 16 + l15) * 32 + quad * 8]);
        asm volatile("s_waitcnt lgkmcnt(0)" ::: "memory");
        __builtin_amdgcn_s_barrier();  // A: all frag reads complete -> wt free
        int kn = (k0 + 32) & 255;
#pragma unroll
        for (int i = 0; i < 5; i++) {
            int ins = w * 5 + i;
            __builtin_amdgcn_global_load_lds(
                (const __attribute__((address_space(1))) void*)(wsrc + (size_t)ins * 16 * CC + kn),
                (__attribute__((address_space(3))) void*)(&wt[ins * 512]), 16, 0, 0);
        }
#pragma unroll
        for (int nt = 0; nt < 2; nt++)
            aqk[nt] = __builtin_amdgcn_mfma_f32_16x16x32_bf16(aqf, bfx[nt], aqk[nt], 0, 0, 0);
#pragma unroll
        for (int mt = 0; mt < 4; mt++)
#pragma unroll
            for (int nt = 0; nt < 2; nt++)
                av[mt][nt] = __builtin_amdgcn_mfma_f32_16x16x32_bf16(avf[mt], bfx[nt], av[mt][nt], 0, 0, 0);
        asm volatile("s_waitcnt vmcnt(0)" ::: "memory");
        __builtin_amdgcn_s_barrier();  // B: next slice resident
    }

    {
        const int ob = (w & 1) * 16 + quad * 4;
        const float* bias = (w < 2) ? bq : bk;
        __bf16* base = (w < 2) ? qb : kb;
#pragma unroll
        for (int nt = 0; nt < 2; nt++) {
            int n = n0 + nt * 16 + l15;
            union { ushort4 u; __bf16 h[4]; } pk;
#pragma unroll
            for (int r = 0; r < 4; r++) pk.h[r] = (__bf16)(aqk[nt][r] + bias[ob + r]);
            *reinterpret_cast<ushort4*>(base + ((size_t)b * NND + n) * CQD + ob) = pk.u;
        }
    }
    __syncthreads();
#pragma unroll
    for (int mt = 0; mt < 4; mt++) {
#pragma unroll
        for (int nt = 0; nt < 2; nt++) {
#pragma unroll
            for (int r = 0; r < 4; r++) {
                int c = (w * 4 + mt) * 16 + quad * 4 + r;
                int nl = nt * 16 + l15;
                xt[c * 32 + (((nl >> 3) ^ (c & 3)) * 8) + (nl & 7)] =
                    (__bf16)(av[mt][nt][r] + bv[c]);
            }
        }
    }
    __syncthreads();
#pragma unroll
    for (int s = 0; s < 4; s++) {
        int c = s * 64 + (tid >> 2);
        int nc = tid & 3;
        bf16x8 vv = ld_bf16x8(&xt[c * 32 + ((nc ^ (c & 3)) * 8)]);
        *reinterpret_cast<bf16x8*>(vb + ((size_t)b * CC + c) * NND + n0 + nc * 8) = vv;
    }
}

// ---------------- fused flash attention + epilogue ----------------
// R12 vs R11: software-pipelined step. sT (QK output) is carried ACROSS
// iterations: iter t runs SM(t) on last iter's sT, then after the barrier
// executes one big independent chunk: QK(t+1) MFMAs + kf(t+2) loads +
// PV(t) (ds_reads -> lgkm-drain -> gll V(t+1) into own Vt slice -> 8 MFMA).
// Breaks the per-step serial chain QK->exp->pack->bar->PV: the QK->exp
// latency now spans a full iteration, and post-barrier each wave has
// ~10 MFMAs of independent work while other waves finish SM. Vt stays
// single-buffered (wave-private: own gll overwrite only after own ds_reads
// drained via lgkmcnt(0)). vmcnt invariant: queue = [kf x2, gll x4] ->
// vmcnt(2) before Vt reads. LDS/occupancy unchanged (2 blocks/CU).
__global__ __launch_bounds__(512, 4) void attention(
    const __bf16* __restrict__ qb, const __bf16* __restrict__ kb,
    const __bf16* __restrict__ vb, const float* __restrict__ gamma,
    const float* __restrict__ x, float* __restrict__ out) {
    __shared__ __align__(16) __bf16 Vt[CC * 64];     // 32768 B, swizzled rows
    __shared__ __align__(16) __bf16 Pt[2][64 * 72];  // 2 x 9216 B, [i][j] stride 72
    __shared__ float lL[2][64];

    const int blk = blockIdx.x;
    const int b = blk & 7;
    const int i0 = (blk >> 3) * 64;
    const int tid = threadIdx.x;
    const int w = tid >> 6;     // 0..7
    const int jh = w >> 2;      // j-half 0/1
    const int iw = w & 3;       // i-slab 0..3
    const int lane = tid & 63;
    const int l15 = lane & 15;
    const int quad = lane >> 4;
    const int l31 = lane & 31;
    const int hi = lane >> 5;
    const f32x4 fzero = {0.f, 0.f, 0.f, 0.f};

    // Q fragment (B-operand): n=i = i0 + iw*16 + l15, k(c) = quad*8..
    bf16x8 qf = ld_bf16x8(qb + ((size_t)b * NND + i0 + iw * 16 + l15) * CQD + quad * 8);

    // K fragments (A-operand), this wave's j-half: j = jh*32 + jt*16 + l15
    const __bf16* kbase = kb + ((size_t)b * NND + jh * 32 + l15) * CQD + quad * 8;
    bf16x8 kf[2];
#pragma unroll
    for (int jt = 0; jt < 2; jt++)
        kf[jt] = ld_bf16x8(kbase + (size_t)(jt * 16) * CQD);

    // global_load_lds source: wave stages c-rows w*32..w*32+31 (wave-private)
    const int vrow = lane >> 3;  // 0..7
    const int vswz = ((lane & 7) ^ vrow) * 8;
    const __bf16* vsrc = vb + ((size_t)(b * CC + w * 32 + vrow)) * NND + vswz;
    __bf16* vdstb = &Vt[(w * 32) * 64];  // wave-uniform base; +lane*16B by HW

    // PV accumulators: 2 i-tiles of 32x32; c = w*32 + crow(reg,hi), i = it*32+l31
    f32x16 acc[2];
#pragma unroll
    for (int it = 0; it < 2; it++)
#pragma unroll
        for (int r = 0; r < 16; r++) acc[it][r] = 0.f;
    float l_i = 0.f;

    // prologue: establish pipeline state for iter 0:
    //   sT = S(0); kf = K(1); VMEM queue = [kf(1) x2, gll V(0) x4]
    f32x4 sT[2];
#pragma unroll
    for (int jt = 0; jt < 2; jt++)
        sT[jt] = __builtin_amdgcn_mfma_f32_16x16x32_bf16(kf[jt], qf, fzero, 0, 0, 0);
#pragma unroll
    for (int jt = 0; jt < 2; jt++)
        kf[jt] = ld_bf16x8(kbase + (size_t)(64 + jt * 16) * CQD);
#pragma unroll
    for (int t = 0; t < 4; t++) {
        __builtin_amdgcn_global_load_lds(
            (const __attribute__((address_space(1))) void*)(vsrc + (size_t)t * 8 * NND),
            (__attribute__((address_space(3))) void*)(vdstb + t * 8 * 64), 16, 0, 0);
    }

#define ATTN_STEP(J0, BUF)                                                    \
    {                                                                         \
        /* SM(t): softmax on sT = S(J0) computed last iter */                 \
        float ps = 0.f;                                                       \
        _Pragma("unroll")                                                     \
        for (int jt = 0; jt < 2; jt++) {                                      \
            union { ushort4 u4; __bf16 h[4]; } pk;                            \
            _Pragma("unroll")                                                 \
            for (int r = 0; r < 4; r++) {                                     \
                float p = __builtin_amdgcn_exp2f(                             \
                    sT[jt][r] * 1.44269504f - 28.85390082f);                  \
                ps += p;                                                      \
                pk.h[r] = (__bf16)p;                                          \
            }                                                                 \
            *reinterpret_cast<ushort4*>(                                      \
                &Pt[BUF][(iw * 16 + l15) * 72 + jh * 32 + jt * 16 + quad * 4]) = pk.u4; \
        }                                                                     \
        l_i += ps;                                                            \
        asm volatile("s_waitcnt lgkmcnt(0)" ::: "memory");                    \
        __builtin_amdgcn_s_barrier();                                         \
        __builtin_amdgcn_s_setprio(1);                                        \
        /* QK(t+1): next step's S, consumed by next SM */                     \
        _Pragma("unroll")                                                     \
        for (int jt = 0; jt < 2; jt++)                                        \
            sT[jt] = __builtin_amdgcn_mfma_f32_16x16x32_bf16(kf[jt], qf, fzero, 0, 0, 0); \
        const int jn2 = ((J0) + 128) & (NND - 1);                             \
        _Pragma("unroll")                                                     \
        for (int jt = 0; jt < 2; jt++)                                        \
            kf[jt] = ld_bf16x8(kbase + (size_t)(jn2 + jt * 16) * CQD);        \
        /* PV(t): V(J0) from own Vt slice + P(J0) from Pt[BUF] */             \
        asm volatile("s_waitcnt vmcnt(2)" ::: "memory");                      \
        __builtin_amdgcn_sched_barrier(0);                                    \
        bf16x8 vfr[4];                                                        \
        bf16x8 pfr[8];                                                        \
        _Pragma("unroll")                                                     \
        for (int kk = 0; kk < 4; kk++) {                                      \
            int slot = (((kk * 2 + hi) ^ (l31 & 7)) * 8);                     \
            vfr[kk] = ld_bf16x8(&Vt[(w * 32 + l31) * 64 + slot]);             \
            _Pragma("unroll")                                                 \
            for (int it = 0; it < 2; it++)                                    \
                pfr[kk * 2 + it] = ld_bf16x8(                                 \
                    &Pt[BUF][(it * 32 + l31) * 72 + kk * 16 + hi * 8]);       \
        }                                                                     \
        asm volatile("s_waitcnt lgkmcnt(0)" ::: "memory");                    \
        __builtin_amdgcn_sched_barrier(0);                                    \
        /* stage V(J0+64) into own slice (reads above are drained) */         \
        _Pragma("unroll")                                                     \
        for (int t = 0; t < 4; t++) {                                         \
            __builtin_amdgcn_global_load_lds(                                 \
                (const __attribute__((address_space(1))) void*)(vsrc + (size_t)t * 8 * NND + (((J0) + 64) & (NND - 1))), \
                (__attribute__((address_space(3))) void*)(vdstb + t * 8 * 64), 16, 0, 0); \
        }                                                                     \
        __builtin_amdgcn_sched_barrier(0);                                    \
        _Pragma("unroll")                                                     \
        for (int kk = 0; kk < 4; kk++)                                        \
            _Pragma("unroll")                                                 \
            for (int it = 0; it < 2; it++)                                    \
                acc[it] = __builtin_amdgcn_mfma_f32_32x32x16_bf16(            \
                    vfr[kk], pfr[kk * 2 + it], acc[it], 0, 0, 0);             \
        __builtin_amdgcn_s_setprio(0);                                        \
    }

    for (int j0 = 0; j0 < NND; j0 += 128) {
        ATTN_STEP(j0, 0)
        ATTN_STEP(j0 + 64, 1)
    }
#undef ATTN_STEP

    // epilogue: combine per-half l sums, then out = gamma * O / l + x
    l_i += __shfl_xor(l_i, 16);
    l_i += __shfl_xor(l_i, 32);
    if (quad == 0) lL[jh][iw * 16 + l15] = l_i;
    __syncthreads();
    float g = gamma[0];
#pragma unroll
    for (int it = 0; it < 2; it++) {
        int i = i0 + it * 32 + l31;
        float linv = 1.0f / (lL[0][it * 32 + l31] + lL[1][it * 32 + l31]);
#pragma unroll
        for (int r = 0; r < 16; r++) {
            int c = w * 32 + (r & 3) + 8 * (r >> 2) + 4 * hi;
            size_t off = ((size_t)b * CC + c) * NND + i;
            out[off] = g * (acc[it][r] * linv) + x[off];
        }
    }
}

extern "C" void kernel_launch(void* const* d_in, const int* in_sizes, int n_in,
                              void* d_out, int out_size, void* d_ws, size_t ws_size,
                              hipStream_t stream) {
    const float* x = (const float*)d_in[0];
    const float* wq = (const float*)d_in[1];
    const float* bq = (const float*)d_in[2];
    const float* wk = (const float*)d_in[3];
    const float* bk = (const float*)d_in[4];
    const float* wv = (const float*)d_in[5];
    const float* bv = (const float*)d_in[6];
    const float* gamma = (const float*)d_in[7];
    float* out = (float*)d_out;

    char* ws = (char*)d_ws;
    __bf16* qb = (__bf16*)ws;                       // 8*4096*32*2  = 2097152
    __bf16* kb = (__bf16*)(ws + 2097152);           // 2097152
    __bf16* vb = (__bf16*)(ws + 2 * 2097152);       // 8*256*4096*2 = 16777216
    __bf16* wqkb = (__bf16*)(ws + 2 * 2097152 + 16777216);           // 32768 (64 rows)
    __bf16* wvb = (__bf16*)(ws + 2 * 2097152 + 16777216 + 32768);    // 131072 (256 rows)

    prep_weights<<<320, 256, 0, stream>>>(wq, wk, wv, wqkb, wvb);
    proj_qkv<<<1024, 256, 0, stream>>>(x, wqkb, wvb, bq, bk, bv, qb, kb, vb);
    attention<<<512, 512, 0, stream>>>(qb, kb, vb, gamma, x, out);
}